// Round 12
// baseline (86.898 us; speedup 1.0000x reference)
//
#include <hip/hip_runtime.h>

// Problem constants (from reference setup_inputs)
constexpr int cB = 32, cC = 6, cT = 64;
constexpr int cK = 8, cN = 128;
constexpr int cS = 32, cP = 64;
constexpr int NCL = cS * cP;          // 2048 centerline points per batch
constexpr int G = 4;                  // blocks per (b,c); 16 points per block
constexpr int PPW = 4;                // points per wave (register-blocked)
constexpr int NIT = 16;               // 1024 slots / 64 lanes
constexpr float F_EPS = 1e-6f;
constexpr float F_THRESHOLD = 0.5f;

// 768 blocks (3/CU), 4 waves/block, 4 pts/wave. ALL 32 table loads (16 cl4 +
// 16 rb2 per lane) are issued upfront into registers -> ONE memory-latency
// round instead of a 16-deep loop-carried prefetch chain (the ~19us stall
// seen in R5-R11: every replay runs on an L2 freshly thrashed by the 268MB
// poison fill, so per-iteration latency is ~1500+ cycles). Both passes then
// compute purely from registers; neighbor vertex rb2[s+1] comes from
// __shfl_down(a[i],1) with lane-63 fixup from a[i+1] (compile-time selects).
__global__ __launch_bounds__(256, 3) void offroad_kernel(
    const float* __restrict__ points,         // (B, C, T, 2)
    const float* __restrict__ road_boundary,  // (B, K, N, 2)
    const float* __restrict__ centerlines,    // (B, S, P, 2)
    float* __restrict__ out)                  // (B, C), pre-zeroed
{
    const int blk  = blockIdx.x;         // 0 .. B*C*G-1
    const int g    = blk & (G - 1);
    const int bc   = blk >> 2;           // b*C + c
    const int b    = bc / cC;
    const int lane = threadIdx.x & 63;
    const int wave = threadIdx.x >> 6;

    const float2* __restrict__ rb2 =
        (const float2*)(road_boundary + (size_t)b * cK * cN * 2);
    const float4* __restrict__ cl4 =
        (const float4*)(centerlines + (size_t)b * NCL * 2);
    const float2* __restrict__ cl2 = (const float2*)cl4;

    // 4 consecutive points for this wave (wave-uniform addresses)
    const int t0 = (g << 4) | (wave << 2);   // in [0, 64)
    const float* pb = points + (((size_t)bc) * cT + t0) * 2;
    float px[PPW], py[PPW];
    #pragma unroll
    for (int p = 0; p < PPW; ++p) { px[p] = pb[2 * p]; py[p] = pb[2 * p + 1]; }

    // ---- Upfront register staging: all 32 loads in flight at once ----
    float4 c[NIT];   // centerline pairs   (64 VGPR)
    float2 a[NIT];   // segment vertices   (32 VGPR)
    #pragma unroll
    for (int i = 0; i < NIT; ++i) c[i] = cl4[lane + 64 * i];
    #pragma unroll
    for (int i = 0; i < NIT; ++i) a[i] = rb2[lane + 64 * i];

    // ---- Pass 1: centerline argmin (first-index tie-break) ----
    float best_d2[PPW];
    int   best_i[PPW];
    #pragma unroll
    for (int p = 0; p < PPW; ++p) { best_d2[p] = 3.4e38f; best_i[p] = 0x7fffffff; }

    #pragma unroll
    for (int i = 0; i < NIT; ++i) {
        const int ia = 2 * (lane + 64 * i);
        #pragma unroll
        for (int p = 0; p < PPW; ++p) {
            float dxa = px[p] - c[i].x, dya = py[p] - c[i].y;
            float d2a = dxa * dxa + dya * dya;
            float dxb = px[p] - c[i].z, dyb = py[p] - c[i].w;
            float d2b = dxb * dxb + dyb * dyb;
            float dmin = d2a; int imin = ia;
            if (d2b < d2a) { dmin = d2b; imin = ia + 1; }  // lower idx on tie
            // per-lane indices ascend with i: strict < keeps first index
            if (dmin < best_d2[p] ||
                (dmin == best_d2[p] && imin < best_i[p])) {
                best_d2[p] = dmin; best_i[p] = imin;
            }
        }
    }
    // argmin butterfly across 64 lanes (tie -> lower index)
    #pragma unroll
    for (int off = 1; off <= 32; off <<= 1) {
        #pragma unroll
        for (int p = 0; p < PPW; ++p) {
            float od2 = __shfl_xor(best_d2[p], off);
            int   oi  = __shfl_xor(best_i[p], off);
            if (od2 < best_d2[p] || (od2 == best_d2[p] && oi < best_i[p])) {
                best_d2[p] = od2; best_i[p] = oi;
            }
        }
    }
    // closest centerline point per point (wave-uniform index -> 4 loads,
    // one latency round)
    float dax[PPW], day[PPW];
    #pragma unroll
    for (int p = 0; p < PPW; ++p) {
        float2 cc = cl2[best_i[p]];
        dax[p] = cc.x - px[p]; day[p] = cc.y - py[p];   // da = a2 - a1
    }

    // ---- Pass 2: segment distance + intersection, all from registers ----
    float min_d2[PPW];
    int   hit[PPW];
    #pragma unroll
    for (int p = 0; p < PPW; ++p) { min_d2[p] = 3.4e38f; hit[p] = 0; }

    #pragma unroll
    for (int i = 0; i < NIT; ++i) {
        // neighbor vertex: lanes 0..62 -> lane+1's a[i]; lane 63:
        //   i even -> lane 0's a[i+1]; i odd -> pad slot (s&127==127)
        const float sdx = __shfl_down(a[i].x, 1);
        const float sdy = __shfl_down(a[i].y, 1);
        const bool last = (lane == 63);
        float nxx, nxy; int valid = 1;
        if (i & 1) {                      // compile-time: pad row for lane 63
            nxx = last ? a[i].x : sdx;    // nx=a -> d=0 (endpoint distance,
            nxy = last ? a[i].y : sdy;    //  >= adjacent real segment's)
            valid = last ? 0 : 1;
        } else {                          // i even <= 14 -> a[i+1] exists
            const float b0x = __shfl(a[i + 1].x, 0);
            const float b0y = __shfl(a[i + 1].y, 0);
            nxx = last ? b0x : sdx;
            nxy = last ? b0y : sdy;
        }

        const float dx = nxx - a[i].x, dy = nxy - a[i].y;
        const float inv_e2 =
            __builtin_amdgcn_rcpf(dx * dx + dy * dy + F_EPS);

        #pragma unroll
        for (int p = 0; p < PPW; ++p) {
            // shared: v1 = p - a (== reference's dp = a1 - b1)
            float v1x = px[p] - a[i].x, v1y = py[p] - a[i].y;
            // point-to-segment distance
            float proj = (v1x * dx + v1y * dy) * inv_e2;
            proj = __builtin_amdgcn_fmed3f(proj, 0.0f, 1.0f);
            float ex = v1x - dx * proj;
            float ey = v1y - dy * proj;
            min_d2[p] = fminf(min_d2[p], ex * ex + ey * ey);
            // intersection, division-free (w = cross(da,db)+EPS):
            //   t,u in [0,1]  <=>  ct*w in [0,w^2] and cu*w in [0,w^2]
            float w  = dax[p] * dy - day[p] * dx + F_EPS;
            float w2 = w * w;
            float ct = (dax[p] * v1y - day[p] * v1x) * w;
            float cu = (dx * v1y - dy * v1x) * w;
            bool inb = (ct >= 0.0f) & (ct <= w2) & (cu >= 0.0f) & (cu <= w2);
            hit[p] |= valid & (int)inb;
        }
    }

    // ---- reduce min_d2 / hit across 64 lanes ----
    #pragma unroll
    for (int off = 1; off <= 32; off <<= 1) {
        #pragma unroll
        for (int p = 0; p < PPW; ++p) {
            min_d2[p] = fminf(min_d2[p], __shfl_xor(min_d2[p], off));
            hit[p]   |= __shfl_xor(hit[p], off);
        }
    }

    // ---- final loss for this wave's 4 points, one atomic per wave ----
    float total = 0.0f;
    #pragma unroll
    for (int p = 0; p < PPW; ++p) {
        float md = sqrtf(min_d2[p]);
        float sd = hit[p] ? md : -md;               // inside -> negative
        total += fmaxf(sd + F_THRESHOLD, 0.0f);
    }
    if (lane == 0)
        atomicAdd(&out[bc], total);
}

extern "C" void kernel_launch(void* const* d_in, const int* in_sizes, int n_in,
                              void* d_out, int out_size, void* d_ws, size_t ws_size,
                              hipStream_t stream) {
    const float* points      = (const float*)d_in[0];
    const float* boundary    = (const float*)d_in[1];
    const float* centerlines = (const float*)d_in[2];
    float* out = (float*)d_out;
    hipMemsetAsync(out, 0, (size_t)out_size * sizeof(float), stream);
    offroad_kernel<<<cB * cC * G, 256, 0, stream>>>(points, boundary, centerlines, out);
}